// Round 16
// baseline (293.601 us; speedup 1.0000x reference)
//
#include <hip/hip_runtime.h>
#include <hip/hip_bf16.h>
#include <hip/hip_fp16.h>

#define HOPS 3
#define NA 50000
#define NP 100000
#define NIN 256
#define NHID 128
#define NOUT 64
#define CAP_A 64
#define CAP_P 40

typedef _Float16 half_t;
typedef __attribute__((ext_vector_type(8))) _Float16 f16x8;
typedef __attribute__((ext_vector_type(4))) float f32x4;
typedef unsigned short ushort_t;

// async global -> LDS, 16 bytes per lane (linear dest: base + lane*16)
__device__ inline void gload16(const void* g, void* l) {
    __builtin_amdgcn_global_load_lds(
        (const __attribute__((address_space(1))) unsigned int*)g,
        (__attribute__((address_space(3))) unsigned int*)l, 16, 0, 0);
}

// ---------- weight transposes+converts (f16) + cnt zeroing (runs BEFORE fused) ----------
__global__ void prep_all(const float* __restrict__ W1_A, const float* __restrict__ W1_P,
                         const float* __restrict__ W2,
                         half_t* __restrict__ WtA, half_t* __restrict__ WtP,
                         half_t* __restrict__ Wt2,
                         int* __restrict__ cntA, int* __restrict__ cntP)
{
    int idx = blockIdx.x * 256 + threadIdx.x;
    const int S1 = NHID * NIN;
    const int SW = 2 * S1 + NOUT * NHID;
    if (idx < S1) {
        int n = idx / NIN, k = idx - n * NIN;
        WtA[idx] = (half_t)W1_A[(size_t)k * NHID + n];
    } else if (idx < 2 * S1) {
        int j = idx - S1;
        int n = j / NIN, k = j - n * NIN;
        WtP[j] = (half_t)W1_P[(size_t)k * NHID + n];
    } else if (idx < SW) {
        int j = idx - 2 * S1;
        int n = j / NHID, k = j - n * NHID;
        Wt2[j] = (half_t)W2[(size_t)k * NOUT + n];
    } else if (idx < SW + NA) {
        cntA[idx - SW] = 0;
    } else if (idx < SW + NA + NP) {
        cntP[idx - SW - NA] = 0;
    }
}

// ---------- FUSED: proj(A)/proj(P)/fill, Bresenham-interleaved block roles ----------
// Role map: c = bid*nProj/nTot; isProj iff (bid+1)*nProj/nTot > c; projIdx=c,
// fillIdx = bid - c. Proj and fill blocks co-resident on every CU for the whole
// dispatch -> fill's scattered-atomic latency hides under proj's barrier stalls.
__global__ __launch_bounds__(256) void fused_proj_fill(
        const float* __restrict__ xA, const float* __restrict__ xP,
        const half_t* __restrict__ WtA_, const half_t* __restrict__ WtP_,
        const float* __restrict__ bA, const float* __restrict__ bP,
        half_t* __restrict__ CA, half_t* __restrict__ CP,
        const int* __restrict__ sA, const int* __restrict__ tA,
        const int* __restrict__ sP, const int* __restrict__ tP,
        int* __restrict__ cntA, int* __restrict__ slotsA,
        int* __restrict__ cntP, int* __restrict__ slotsP,
        int nE, int gA, int nProj, int nTot)
{
    __shared__ half_t Alds[64][40];
    __shared__ half_t Wlds[128][40];
    const int bid = blockIdx.x;
    const int tid = threadIdx.x;

    const int c  = (int)(((long long)bid * nProj) / nTot);
    const int c2 = (int)(((long long)(bid + 1) * nProj) / nTot);

    if (c2 == c) {
        // ---------------- fill part ----------------
        int e = (bid - c) * 256 + tid;   // fillIdx = bid - c (c proj blocks precede)
        if (e < nE) {
            int si = sA[e];
            int cc = atomicAdd(&cntA[si], 1);
            if (cc < CAP_A) slotsA[(size_t)si * CAP_A + cc] = tA[e];
        } else if (e < 2 * nE) {
            int k = e - nE;
            int si = sP[k];
            int cc = atomicAdd(&cntP[si], 1);
            if (cc < CAP_P) slotsP[(size_t)si * CAP_P + cc] = tP[k];
        }
        return;
    }

    // ---------------- proj part ----------------
    const int pid = c;
    const bool isA = pid < gA;
    const float* A = isA ? xA : xP;
    const half_t* Wt = isA ? WtA_ : WtP_;
    const float* bias = isA ? bA : bP;
    half_t* Chf = isA ? CA : CP;
    const int M = isA ? NA : NP;
    const int br = (isA ? pid : pid - gA) * 64;

    int wv = tid >> 6;
    int l = tid & 63;
    int fl = l & 15;
    int kg = l >> 4;

    int sr = tid >> 2;
    int skp = (tid & 3) * 8;
    int sgr = br + sr; if (sgr >= M) sgr = M - 1;
    int sn = tid >> 1;
    int skq = (tid & 1) * 16;

    f32x4 acc[8];
    #pragma unroll
    for (int cc = 0; cc < 8; ++cc) acc[cc] = (f32x4){0.f, 0.f, 0.f, 0.f};

    for (int k0 = 0; k0 < NIN; k0 += 32) {
        const float4* ap = (const float4*)(A + (size_t)sgr * NIN + k0 + skp);
        float4 v0 = ap[0], v1 = ap[1];
        union { half_t s[8]; int4 v; } pk;
        pk.s[0] = (half_t)v0.x; pk.s[1] = (half_t)v0.y;
        pk.s[2] = (half_t)v0.z; pk.s[3] = (half_t)v0.w;
        pk.s[4] = (half_t)v1.x; pk.s[5] = (half_t)v1.y;
        pk.s[6] = (half_t)v1.z; pk.s[7] = (half_t)v1.w;
        *(int4*)&Alds[sr][skp] = pk.v;
        const int4* wp = (const int4*)(Wt + (size_t)sn * NIN + k0 + skq);
        int4 w0 = wp[0], w1 = wp[1];
        *(int4*)&Wlds[sn][skq] = w0;
        *(int4*)&Wlds[sn][skq + 8] = w1;
        __syncthreads();

        f16x8 afr = *(f16x8*)&Alds[wv * 16 + fl][kg * 8];
        #pragma unroll
        for (int cc = 0; cc < 8; ++cc) {
            f16x8 bfr = *(f16x8*)&Wlds[cc * 16 + fl][kg * 8];
            acc[cc] = __builtin_amdgcn_mfma_f32_16x16x32_f16(afr, bfr, acc[cc], 0, 0, 0);
        }
        __syncthreads();
    }

    int rj = kg * 4;
    #pragma unroll
    for (int cc = 0; cc < 8; ++cc) {
        int col = cc * 16 + fl;
        float bb = bias[col];
        #pragma unroll
        for (int j = 0; j < 4; ++j) {
            int grow = br + wv * 16 + rj + j;
            if (grow < M) {
                float v = fmaxf(acc[cc][j] + bb, 0.f);
                Chf[(size_t)grow * NHID + col] = (half_t)v;
            }
        }
    }
}

// ---------- output: C[M,64] = Ahf[M,128] @ W2 + b2, single-stage f16 MFMA ----------
__global__ __launch_bounds__(256) void out_mfma(const half_t* __restrict__ Ahf,
        const half_t* __restrict__ Wt, const float* __restrict__ b,
        float* __restrict__ C, int M)
{
    __shared__ half_t Sb[64 * 128];
    const int tid = threadIdx.x;
    const int wv = tid >> 6, l = tid & 63;
    const int fl = l & 15, kg = l >> 4;
    const int br = blockIdx.x * 64;
    const int srow = l >> 4, schk = l & 15;

    #pragma unroll
    for (int i = 0; i < 4; ++i) {
        int r = (wv * 4 + i) * 4 + srow;
        int gr = br + r; if (gr >= M) gr = M - 1;
        int ck = (schk ^ (r & 7)) * 8;
        gload16(Ahf + (size_t)gr * NHID + ck, &Sb[(wv * 4 + i) * 512]);
    }

    f32x4 acc[4];
    #pragma unroll
    for (int c = 0; c < 4; ++c) acc[c] = (f32x4){0.f, 0.f, 0.f, 0.f};

    f16x8 Bf[16];
    #pragma unroll
    for (int ks = 0; ks < 4; ++ks)
        #pragma unroll
        for (int cc = 0; cc < 4; ++cc)
            Bf[ks * 4 + cc] = *(const f16x8*)(Wt + (size_t)(cc * 16 + fl) * NHID
                                              + ks * 32 + kg * 8);
    __syncthreads();

    const int R = wv * 16 + fl;
    const int rx = R & 7;
    #pragma unroll
    for (int ks = 0; ks < 4; ++ks) {
        int chunk = (ks * 4 + kg) ^ rx;
        f16x8 af = *(const f16x8*)&Sb[R * 128 + chunk * 8];
        #pragma unroll
        for (int cc = 0; cc < 4; ++cc)
            acc[cc] = __builtin_amdgcn_mfma_f32_16x16x32_f16(af, Bf[ks * 4 + cc],
                                                             acc[cc], 0, 0, 0);
    }

    #pragma unroll
    for (int cc = 0; cc < 4; ++cc) {
        int col = cc * 16 + fl;
        float bb = b[col];
        #pragma unroll
        for (int j = 0; j < 4; ++j) {
            int grow = br + wv * 16 + kg * 4 + j;
            if (grow < M) C[(size_t)grow * NOUT + col] = acc[cc][j] + bb;
        }
    }
}

// ---------- x-side scalars for ALL hops: 4 NODES PER WAVE, 16 lanes/node ----------
__global__ __launch_bounds__(256) void xdots_kernel(
    const half_t* __restrict__ xAh, const half_t* __restrict__ xPh,
    const float* __restrict__ attn1, const float* __restrict__ attn2,
    float* __restrict__ x1A, float* __restrict__ w2A, float* __restrict__ h1Ai,
    float* __restrict__ x1P, float* __restrict__ w2P, float* __restrict__ h1Pi)
{
    int tid = threadIdx.x;
    int lane = tid & 63;
    int grp = lane >> 4, fl = lane & 15;
    int wid = (blockIdx.x * 256 + tid) >> 6;
    int ng = wid * 4 + grp;
    if (ng >= NA + NP) return;
    bool isA = ng < NA;
    int n = isA ? ng : ng - NA;
    int etype = isA ? 0 : 1;

    const half_t* x = (isA ? xAh : xPh) + (size_t)n * NHID + fl * 8;
    union { int4 v; half_t h[8]; } xc;
    xc.v = *(const int4*)x;
    float xf[8];
    #pragma unroll
    for (int j = 0; j < 8; ++j) xf[j] = (float)xc.h[j];

    float s[7];
    #pragma unroll
    for (int i = 0; i < 3; ++i) {
        const float* a1 = attn1 + (size_t)(i * 2 + etype) * NHID + fl * 8;
        const float* a2 = attn2 + (size_t)(i * 2 + etype) * NHID + fl * 8;
        float4 p0 = *(const float4*)a1, p1 = *(const float4*)(a1 + 4);
        float4 q0 = *(const float4*)a2, q1 = *(const float4*)(a2 + 4);
        float t1 = xf[0] * p0.x + xf[1] * p0.y + xf[2] * p0.z + xf[3] * p0.w
                 + xf[4] * p1.x + xf[5] * p1.y + xf[6] * p1.z + xf[7] * p1.w;
        float t2 = xf[0] * q0.x + xf[1] * q0.y + xf[2] * q0.z + xf[3] * q0.w
                 + xf[4] * q1.x + xf[5] * q1.y + xf[6] * q1.z + xf[7] * q1.w;
        s[i] = t1;
        s[3 + i] = t2;
    }
    {
        const float* a2o = attn2 + (size_t)(1 - etype) * NHID + fl * 8;
        float4 q0 = *(const float4*)a2o, q1 = *(const float4*)(a2o + 4);
        s[6] = xf[0] * q0.x + xf[1] * q0.y + xf[2] * q0.z + xf[3] * q0.w
             + xf[4] * q1.x + xf[5] * q1.y + xf[6] * q1.z + xf[7] * q1.w;
    }
    #pragma unroll
    for (int m = 1; m <= 8; m <<= 1)
        #pragma unroll
        for (int i = 0; i < 7; ++i) s[i] += __shfl_xor(s[i], m, 64);

    if (fl == 0) {
        int N = isA ? NA : NP;
        float* x1 = isA ? x1A : x1P;
        float* w2 = isA ? w2A : w2P;
        #pragma unroll
        for (int i = 0; i < 3; ++i) {
            x1[(size_t)i * N + n] = s[i];
            float v = s[i] + s[3 + i];
            v = v > 0.f ? v : 0.2f * v;
            w2[(size_t)i * N + n] = __expf(v);
        }
        (isA ? h1Ai : h1Pi)[n] = s[6];
    }
}

// ---------- fused A+P aggregation: 4 NODES PER WAVE, 16 lanes per node ----------
__global__ __launch_bounds__(256) void agg_fused(
    const half_t* __restrict__ xAh, const half_t* __restrict__ xPh,
    const half_t* __restrict__ hAg, const half_t* __restrict__ hPg,
    const float* __restrict__ x1Ah, const float* __restrict__ x1Ph,
    const float* __restrict__ w2Ah, const float* __restrict__ w2Ph,
    const float* __restrict__ h1Agc, const float* __restrict__ h1Pgc,
    const int* __restrict__ cntA, const int* __restrict__ slotsA,
    const int* __restrict__ cntP, const int* __restrict__ slotsP,
    const float* __restrict__ a2nA, const float* __restrict__ a2nP,
    half_t* __restrict__ hAout, half_t* __restrict__ hPout,
    float* __restrict__ h1Aout, float* __restrict__ h1Pout,
    int nodes)
{
    __shared__ float2 ew[4][4][16];   // [wave][group][slot] : (t as bits, w)
    int tid = threadIdx.x;
    int wv = tid >> 6;
    int lane = tid & 63;
    int grp = lane >> 4, fl = lane & 15;
    int wid = (blockIdx.x * 256 + tid) >> 6;
    int ng = wid * 4 + grp;
    if (ng >= nodes) return;
    bool isA = ng < NA;
    int n = isA ? ng : ng - NA;
    int deg; const int* sl; const half_t* hbf; const float* h1g; float x1v;
    if (isA) {
        deg = cntA[n]; if (deg > CAP_A) deg = CAP_A;
        sl = slotsA + (size_t)n * CAP_A; hbf = hPg; h1g = h1Pgc; x1v = x1Ah[n];
    } else {
        deg = cntP[n]; if (deg > CAP_P) deg = CAP_P;
        sl = slotsP + (size_t)n * CAP_P; hbf = hAg; h1g = h1Agc; x1v = x1Ph[n];
    }

    float acc[8] = {};
    float divacc = 0.f;

    for (int c0 = 0; c0 < deg; c0 += 16) {
        int idx = c0 + fl;
        int tl = 0; float wl = 0.f;
        if (idx < deg) {
            tl = sl[idx];
            float v = x1v + h1g[tl];
            v = v > 0.f ? v : 0.2f * v;
            wl = __expf(v);
        }
        divacc += wl;
        ew[wv][grp][fl] = make_float2(__int_as_float(tl), wl);

        int rounds = deg - c0; if (rounds > 16) rounds = 16;
        float2 tw = ew[wv][grp][0];
        int4 ra = *(const int4*)(hbf + (size_t)__float_as_int(tw.x) * NHID + fl * 8);
        for (int j = 0; j < rounds; ++j) {
            float w = tw.y;
            union { int4 v; half_t h[8]; } cur;
            cur.v = ra;
            if (j + 1 < rounds) {
                tw = ew[wv][grp][j + 1];
                ra = *(const int4*)(hbf + (size_t)__float_as_int(tw.x) * NHID + fl * 8);
            }
            acc[0] = fmaf(w, (float)cur.h[0], acc[0]);
            acc[1] = fmaf(w, (float)cur.h[1], acc[1]);
            acc[2] = fmaf(w, (float)cur.h[2], acc[2]);
            acc[3] = fmaf(w, (float)cur.h[3], acc[3]);
            acc[4] = fmaf(w, (float)cur.h[4], acc[4]);
            acc[5] = fmaf(w, (float)cur.h[5], acc[5]);
            acc[6] = fmaf(w, (float)cur.h[6], acc[6]);
            acc[7] = fmaf(w, (float)cur.h[7], acc[7]);
        }
    }

    // div reduce within the 16-lane group
    #pragma unroll
    for (int m = 1; m <= 8; m <<= 1) divacc += __shfl_xor(divacc, m, 64);

    // self term + epilogue: each lane finishes its 8 features
    float w2v = isA ? w2Ah[n] : w2Ph[n];
    const half_t* xb = (isA ? xAh : xPh) + (size_t)n * NHID + fl * 8;
    union { int4 v; half_t h[8]; } xc;
    xc.v = *(const int4*)xb;
    #pragma unroll
    for (int j = 0; j < 8; ++j) acc[j] = fmaf(w2v, (float)xc.h[j], acc[j]);
    float dv = divacc + w2v;
    float inv = 1.f / dv;

    const float* a2 = isA ? a2nA : a2nP;
    float4 av0 = *(const float4*)(a2 + fl * 8);
    float4 av1 = *(const float4*)(a2 + fl * 8 + 4);
    float avf[8] = {av0.x, av0.y, av0.z, av0.w, av1.x, av1.y, av1.z, av1.w};

    float o[8], s = 0.f;
    #pragma unroll
    for (int j = 0; j < 8; ++j) {
        float v = acc[j] * inv;
        o[j] = v > 0.f ? v : (__expf(v) - 1.f);
        s = fmaf(o[j], avf[j], s);
    }
    #pragma unroll
    for (int m = 1; m <= 8; m <<= 1) s += __shfl_xor(s, m, 64);

    union { half_t h[8]; int4 v; } pk;
    #pragma unroll
    for (int j = 0; j < 8; ++j) pk.h[j] = (half_t)o[j];
    *(int4*)((isA ? hAout : hPout) + (size_t)n * NHID + fl * 8) = pk.v;
    if (fl == 0) (isA ? h1Aout : h1Pout)[n] = s;
}

extern "C" void kernel_launch(void* const* d_in, const int* in_sizes, int n_in,
                              void* d_out, int out_size, void* d_ws, size_t ws_size,
                              hipStream_t stream)
{
    const float* x_A  = (const float*)d_in[0];
    const float* x_P  = (const float*)d_in[1];
    const int*   sAP  = (const int*)d_in[2];
    const int*   tAP  = (const int*)d_in[3];
    const int*   sPA  = (const int*)d_in[4];
    const int*   tPA  = (const int*)d_in[5];
    const float* W1_A = (const float*)d_in[6];
    const float* b1_A = (const float*)d_in[7];
    const float* W1_P = (const float*)d_in[8];
    const float* b1_P = (const float*)d_in[9];
    const float* attn1 = (const float*)d_in[10];
    const float* attn2 = (const float*)d_in[11];
    const float* W2   = (const float*)d_in[12];
    const float* b2   = (const float*)d_in[13];
    float* out = (float*)d_out;
    int nE = in_sizes[2];

    char* ws = (char*)d_ws;
    size_t off = 0;
    auto alloc = [&](size_t bytes) -> void* {
        void* p = ws + off;
        off += (bytes + 255) & ~(size_t)255;
        return p;
    };
    half_t* xAh  = (half_t*)alloc((size_t)NA * NHID * 2);
    half_t* xPh  = (half_t*)alloc((size_t)NP * NHID * 2);
    half_t* hAh[2] = {(half_t*)alloc((size_t)NA * NHID * 2),
                      (half_t*)alloc((size_t)NA * NHID * 2)};
    half_t* hPh[2] = {(half_t*)alloc((size_t)NP * NHID * 2),
                      (half_t*)alloc((size_t)NP * NHID * 2)};
    float* x1A = (float*)alloc((size_t)3 * NA * 4);
    float* w2A = (float*)alloc((size_t)3 * NA * 4);
    float* x1P = (float*)alloc((size_t)3 * NP * 4);
    float* w2P = (float*)alloc((size_t)3 * NP * 4);
    float* h1Ai = (float*)alloc(NA * 4);
    float* h1Pi = (float*)alloc(NP * 4);
    float* h1Ab[2] = {(float*)alloc(NA * 4), (float*)alloc(NA * 4)};
    float* h1Pb[2] = {(float*)alloc(NP * 4), (float*)alloc(NP * 4)};
    int* cntA  = (int*)alloc(NA * 4);
    int* cntP  = (int*)alloc(NP * 4);
    int* slotsA = (int*)alloc((size_t)NA * CAP_A * 4);
    int* slotsP = (int*)alloc((size_t)NP * CAP_P * 4);
    half_t* WtA = (half_t*)alloc((size_t)NHID * NIN * 2);
    half_t* WtP = (half_t*)alloc((size_t)NHID * NIN * 2);
    half_t* Wt2 = (half_t*)alloc((size_t)NOUT * NHID * 2);

    // weights -> f16 transposed + cnt zeroing (before fused kernel)
    int prepN = 2 * NHID * NIN + NOUT * NHID + NA + NP;
    prep_all<<<(prepN + 255) / 256, 256, 0, stream>>>(W1_A, W1_P, W2, WtA, WtP, Wt2,
                                                      cntA, cntP);

    // FUSED proj+fill, interleaved block roles
    int gA = (NA + 63) / 64, gP = (NP + 63) / 64;
    int nProj = gA + gP;
    int fillBlocks = (2 * nE + 255) / 256;
    int nTot = nProj + fillBlocks;
    fused_proj_fill<<<nTot, 256, 0, stream>>>(
        x_A, x_P, WtA, WtP, b1_A, b1_P, xAh, xPh,
        sAP, tAP, sPA, tPA, cntA, slotsA, cntP, slotsP,
        nE, gA, nProj, nTot);

    // x-side scalars for all hops (4 nodes/wave)
    xdots_kernel<<<(NA + NP + 15) / 16, 256, 0, stream>>>(
        xAh, xPh, attn1, attn2, x1A, w2A, h1Ai, x1P, w2P, h1Pi);

    const half_t* hAg = xAh;
    const half_t* hPg = xPh;
    const float* h1Ac = h1Ai;
    const float* h1Pc = h1Pi;

    for (int i = 0; i < HOPS; ++i) {
        int last = (i == HOPS - 1);
        int nodes = last ? NA : (NA + NP);
        const float* a2nA_ = last ? attn2 : attn2 + (size_t)((i + 1) * 2 + 1) * NHID;
        const float* a2nP_ = last ? attn2 : attn2 + (size_t)((i + 1) * 2 + 0) * NHID;
        agg_fused<<<(nodes + 15) / 16, 256, 0, stream>>>(
            xAh, xPh, hAg, hPg,
            x1A + (size_t)i * NA, x1P + (size_t)i * NP,
            w2A + (size_t)i * NA, w2P + (size_t)i * NP,
            h1Ac, h1Pc,
            cntA, slotsA, cntP, slotsP,
            a2nA_, a2nP_,
            hAh[i & 1], hPh[i & 1], h1Ab[i & 1], h1Pb[i & 1],
            nodes);
        hAg = hAh[i & 1]; hPg = hPh[i & 1];
        h1Ac = h1Ab[i & 1]; h1Pc = h1Pb[i & 1];
    }

    out_mfma<<<(NA + 63) / 64, 256, 0, stream>>>(hAg, Wt2, b2, out, NA);
}

// Round 17
// 268.099 us; speedup vs baseline: 1.0951x; 1.0951x over previous
//
#include <hip/hip_runtime.h>
#include <hip/hip_bf16.h>
#include <hip/hip_fp16.h>

#define HOPS 3
#define NA 50000
#define NP 100000
#define NIN 256
#define NHID 128
#define NOUT 64
#define CAP_A 64
#define CAP_P 40

typedef _Float16 half_t;
typedef __attribute__((ext_vector_type(8))) _Float16 f16x8;
typedef __attribute__((ext_vector_type(4))) float f32x4;
typedef unsigned short ushort_t;

// async global -> LDS, 16 bytes per lane (linear dest: base + lane*16)
__device__ inline void gload16(const void* g, void* l) {
    __builtin_amdgcn_global_load_lds(
        (const __attribute__((address_space(1))) unsigned int*)g,
        (__attribute__((address_space(3))) unsigned int*)l, 16, 0, 0);
}

// ---------- weight transposes+converts (f16) + cnt zeroing (runs BEFORE fused) ----------
__global__ void prep_all(const float* __restrict__ W1_A, const float* __restrict__ W1_P,
                         const float* __restrict__ W2,
                         half_t* __restrict__ WtA, half_t* __restrict__ WtP,
                         half_t* __restrict__ Wt2,
                         int* __restrict__ cntA, int* __restrict__ cntP)
{
    int idx = blockIdx.x * 256 + threadIdx.x;
    const int S1 = NHID * NIN;
    const int SW = 2 * S1 + NOUT * NHID;
    if (idx < S1) {
        int n = idx / NIN, k = idx - n * NIN;
        WtA[idx] = (half_t)W1_A[(size_t)k * NHID + n];
    } else if (idx < 2 * S1) {
        int j = idx - S1;
        int n = j / NIN, k = j - n * NIN;
        WtP[j] = (half_t)W1_P[(size_t)k * NHID + n];
    } else if (idx < SW) {
        int j = idx - 2 * S1;
        int n = j / NHID, k = j - n * NHID;
        Wt2[j] = (half_t)W2[(size_t)k * NOUT + n];
    } else if (idx < SW + NA) {
        cntA[idx - SW] = 0;
    } else if (idx < SW + NA + NP) {
        cntP[idx - SW - NA] = 0;
    }
}

// ---------- FUSED: proj(A) blocks [0,gA) | proj(P) blocks [gA,gAB) | fill rest ----------
// proj: R2/R9 measured-best structure (f16). fill: padded-CSR scatter runs as
// tail filler after proj blocks drain (measured best ordering; true
// concurrency with proj is net-negative due to L2 contention - R16).
__global__ __launch_bounds__(256) void fused_proj_fill(
        const float* __restrict__ xA, const float* __restrict__ xP,
        const half_t* __restrict__ WtA_, const half_t* __restrict__ WtP_,
        const float* __restrict__ bA, const float* __restrict__ bP,
        half_t* __restrict__ CA, half_t* __restrict__ CP,
        const int* __restrict__ sA, const int* __restrict__ tA,
        const int* __restrict__ sP, const int* __restrict__ tP,
        int* __restrict__ cntA, int* __restrict__ slotsA,
        int* __restrict__ cntP, int* __restrict__ slotsP,
        int nE, int gA, int gAB)
{
    __shared__ half_t Alds[64][40];
    __shared__ half_t Wlds[128][40];
    const int bid = blockIdx.x;
    const int tid = threadIdx.x;

    if (bid >= gAB) {
        // ---------------- fill part ----------------
        int e = (bid - gAB) * 256 + tid;
        if (e < nE) {
            int si = sA[e];
            int c = atomicAdd(&cntA[si], 1);
            if (c < CAP_A) slotsA[(size_t)si * CAP_A + c] = tA[e];
        } else if (e < 2 * nE) {
            int k = e - nE;
            int si = sP[k];
            int c = atomicAdd(&cntP[si], 1);
            if (c < CAP_P) slotsP[(size_t)si * CAP_P + c] = tP[k];
        }
        return;
    }

    // ---------------- proj part ----------------
    const bool isA = bid < gA;
    const float* A = isA ? xA : xP;
    const half_t* Wt = isA ? WtA_ : WtP_;
    const float* bias = isA ? bA : bP;
    half_t* Chf = isA ? CA : CP;
    const int M = isA ? NA : NP;
    const int br = (isA ? bid : bid - gA) * 64;

    int wv = tid >> 6;
    int l = tid & 63;
    int fl = l & 15;
    int kg = l >> 4;

    int sr = tid >> 2;
    int skp = (tid & 3) * 8;
    int sgr = br + sr; if (sgr >= M) sgr = M - 1;
    int sn = tid >> 1;
    int skq = (tid & 1) * 16;

    f32x4 acc[8];
    #pragma unroll
    for (int c = 0; c < 8; ++c) acc[c] = (f32x4){0.f, 0.f, 0.f, 0.f};

    for (int k0 = 0; k0 < NIN; k0 += 32) {
        const float4* ap = (const float4*)(A + (size_t)sgr * NIN + k0 + skp);
        float4 v0 = ap[0], v1 = ap[1];
        union { half_t s[8]; int4 v; } pk;
        pk.s[0] = (half_t)v0.x; pk.s[1] = (half_t)v0.y;
        pk.s[2] = (half_t)v0.z; pk.s[3] = (half_t)v0.w;
        pk.s[4] = (half_t)v1.x; pk.s[5] = (half_t)v1.y;
        pk.s[6] = (half_t)v1.z; pk.s[7] = (half_t)v1.w;
        *(int4*)&Alds[sr][skp] = pk.v;
        const int4* wp = (const int4*)(Wt + (size_t)sn * NIN + k0 + skq);
        int4 w0 = wp[0], w1 = wp[1];
        *(int4*)&Wlds[sn][skq] = w0;
        *(int4*)&Wlds[sn][skq + 8] = w1;
        __syncthreads();

        f16x8 afr = *(f16x8*)&Alds[wv * 16 + fl][kg * 8];
        #pragma unroll
        for (int c = 0; c < 8; ++c) {
            f16x8 bfr = *(f16x8*)&Wlds[c * 16 + fl][kg * 8];
            acc[c] = __builtin_amdgcn_mfma_f32_16x16x32_f16(afr, bfr, acc[c], 0, 0, 0);
        }
        __syncthreads();
    }

    int rj = kg * 4;
    #pragma unroll
    for (int c = 0; c < 8; ++c) {
        int col = c * 16 + fl;
        float bb = bias[col];
        #pragma unroll
        for (int j = 0; j < 4; ++j) {
            int grow = br + wv * 16 + rj + j;
            if (grow < M) {
                float v = fmaxf(acc[c][j] + bb, 0.f);
                Chf[(size_t)grow * NHID + col] = (half_t)v;
            }
        }
    }
}

// ---------- output: C[M,64] = Ahf[M,128] @ W2 + b2, single-stage f16 MFMA ----------
__global__ __launch_bounds__(256) void out_mfma(const half_t* __restrict__ Ahf,
        const half_t* __restrict__ Wt, const float* __restrict__ b,
        float* __restrict__ C, int M)
{
    __shared__ half_t Sb[64 * 128];
    const int tid = threadIdx.x;
    const int wv = tid >> 6, l = tid & 63;
    const int fl = l & 15, kg = l >> 4;
    const int br = blockIdx.x * 64;
    const int srow = l >> 4, schk = l & 15;

    #pragma unroll
    for (int i = 0; i < 4; ++i) {
        int r = (wv * 4 + i) * 4 + srow;
        int gr = br + r; if (gr >= M) gr = M - 1;
        int ck = (schk ^ (r & 7)) * 8;
        gload16(Ahf + (size_t)gr * NHID + ck, &Sb[(wv * 4 + i) * 512]);
    }

    f32x4 acc[4];
    #pragma unroll
    for (int c = 0; c < 4; ++c) acc[c] = (f32x4){0.f, 0.f, 0.f, 0.f};

    f16x8 Bf[16];
    #pragma unroll
    for (int ks = 0; ks < 4; ++ks)
        #pragma unroll
        for (int cc = 0; cc < 4; ++cc)
            Bf[ks * 4 + cc] = *(const f16x8*)(Wt + (size_t)(cc * 16 + fl) * NHID
                                              + ks * 32 + kg * 8);
    __syncthreads();

    const int R = wv * 16 + fl;
    const int rx = R & 7;
    #pragma unroll
    for (int ks = 0; ks < 4; ++ks) {
        int chunk = (ks * 4 + kg) ^ rx;
        f16x8 af = *(const f16x8*)&Sb[R * 128 + chunk * 8];
        #pragma unroll
        for (int cc = 0; cc < 4; ++cc)
            acc[cc] = __builtin_amdgcn_mfma_f32_16x16x32_f16(af, Bf[ks * 4 + cc],
                                                             acc[cc], 0, 0, 0);
    }

    #pragma unroll
    for (int cc = 0; cc < 4; ++cc) {
        int col = cc * 16 + fl;
        float bb = b[col];
        #pragma unroll
        for (int j = 0; j < 4; ++j) {
            int grow = br + wv * 16 + kg * 4 + j;
            if (grow < M) C[(size_t)grow * NOUT + col] = acc[cc][j] + bb;
        }
    }
}

// ---------- x-side scalars for ALL hops: 4 NODES PER WAVE, 16 lanes/node ----------
__global__ __launch_bounds__(256) void xdots_kernel(
    const half_t* __restrict__ xAh, const half_t* __restrict__ xPh,
    const float* __restrict__ attn1, const float* __restrict__ attn2,
    float* __restrict__ x1A, float* __restrict__ w2A, float* __restrict__ h1Ai,
    float* __restrict__ x1P, float* __restrict__ w2P, float* __restrict__ h1Pi)
{
    int tid = threadIdx.x;
    int lane = tid & 63;
    int grp = lane >> 4, fl = lane & 15;
    int wid = (blockIdx.x * 256 + tid) >> 6;
    int ng = wid * 4 + grp;
    if (ng >= NA + NP) return;
    bool isA = ng < NA;
    int n = isA ? ng : ng - NA;
    int etype = isA ? 0 : 1;

    const half_t* x = (isA ? xAh : xPh) + (size_t)n * NHID + fl * 8;
    union { int4 v; half_t h[8]; } xc;
    xc.v = *(const int4*)x;
    float xf[8];
    #pragma unroll
    for (int j = 0; j < 8; ++j) xf[j] = (float)xc.h[j];

    float s[7];
    #pragma unroll
    for (int i = 0; i < 3; ++i) {
        const float* a1 = attn1 + (size_t)(i * 2 + etype) * NHID + fl * 8;
        const float* a2 = attn2 + (size_t)(i * 2 + etype) * NHID + fl * 8;
        float4 p0 = *(const float4*)a1, p1 = *(const float4*)(a1 + 4);
        float4 q0 = *(const float4*)a2, q1 = *(const float4*)(a2 + 4);
        float t1 = xf[0] * p0.x + xf[1] * p0.y + xf[2] * p0.z + xf[3] * p0.w
                 + xf[4] * p1.x + xf[5] * p1.y + xf[6] * p1.z + xf[7] * p1.w;
        float t2 = xf[0] * q0.x + xf[1] * q0.y + xf[2] * q0.z + xf[3] * q0.w
                 + xf[4] * q1.x + xf[5] * q1.y + xf[6] * q1.z + xf[7] * q1.w;
        s[i] = t1;
        s[3 + i] = t2;
    }
    {
        const float* a2o = attn2 + (size_t)(1 - etype) * NHID + fl * 8;
        float4 q0 = *(const float4*)a2o, q1 = *(const float4*)(a2o + 4);
        s[6] = xf[0] * q0.x + xf[1] * q0.y + xf[2] * q0.z + xf[3] * q0.w
             + xf[4] * q1.x + xf[5] * q1.y + xf[6] * q1.z + xf[7] * q1.w;
    }
    #pragma unroll
    for (int m = 1; m <= 8; m <<= 1)
        #pragma unroll
        for (int i = 0; i < 7; ++i) s[i] += __shfl_xor(s[i], m, 64);

    if (fl == 0) {
        int N = isA ? NA : NP;
        float* x1 = isA ? x1A : x1P;
        float* w2 = isA ? w2A : w2P;
        #pragma unroll
        for (int i = 0; i < 3; ++i) {
            x1[(size_t)i * N + n] = s[i];
            float v = s[i] + s[3 + i];
            v = v > 0.f ? v : 0.2f * v;
            w2[(size_t)i * N + n] = __expf(v);
        }
        (isA ? h1Ai : h1Pi)[n] = s[6];
    }
}

// ---------- fused A+P aggregation: 4 NODES PER WAVE, 16 lanes per node ----------
__global__ __launch_bounds__(256) void agg_fused(
    const half_t* __restrict__ xAh, const half_t* __restrict__ xPh,
    const half_t* __restrict__ hAg, const half_t* __restrict__ hPg,
    const float* __restrict__ x1Ah, const float* __restrict__ x1Ph,
    const float* __restrict__ w2Ah, const float* __restrict__ w2Ph,
    const float* __restrict__ h1Agc, const float* __restrict__ h1Pgc,
    const int* __restrict__ cntA, const int* __restrict__ slotsA,
    const int* __restrict__ cntP, const int* __restrict__ slotsP,
    const float* __restrict__ a2nA, const float* __restrict__ a2nP,
    half_t* __restrict__ hAout, half_t* __restrict__ hPout,
    float* __restrict__ h1Aout, float* __restrict__ h1Pout,
    int nodes)
{
    __shared__ float2 ew[4][4][16];   // [wave][group][slot] : (t as bits, w)
    int tid = threadIdx.x;
    int wv = tid >> 6;
    int lane = tid & 63;
    int grp = lane >> 4, fl = lane & 15;
    int wid = (blockIdx.x * 256 + tid) >> 6;
    int ng = wid * 4 + grp;
    if (ng >= nodes) return;
    bool isA = ng < NA;
    int n = isA ? ng : ng - NA;
    int deg; const int* sl; const half_t* hbf; const float* h1g; float x1v;
    if (isA) {
        deg = cntA[n]; if (deg > CAP_A) deg = CAP_A;
        sl = slotsA + (size_t)n * CAP_A; hbf = hPg; h1g = h1Pgc; x1v = x1Ah[n];
    } else {
        deg = cntP[n]; if (deg > CAP_P) deg = CAP_P;
        sl = slotsP + (size_t)n * CAP_P; hbf = hAg; h1g = h1Agc; x1v = x1Ph[n];
    }

    float acc[8] = {};
    float divacc = 0.f;

    for (int c0 = 0; c0 < deg; c0 += 16) {
        int idx = c0 + fl;
        int tl = 0; float wl = 0.f;
        if (idx < deg) {
            tl = sl[idx];
            float v = x1v + h1g[tl];
            v = v > 0.f ? v : 0.2f * v;
            wl = __expf(v);
        }
        divacc += wl;
        ew[wv][grp][fl] = make_float2(__int_as_float(tl), wl);

        int rounds = deg - c0; if (rounds > 16) rounds = 16;
        float2 tw = ew[wv][grp][0];
        int4 ra = *(const int4*)(hbf + (size_t)__float_as_int(tw.x) * NHID + fl * 8);
        for (int j = 0; j < rounds; ++j) {
            float w = tw.y;
            union { int4 v; half_t h[8]; } cur;
            cur.v = ra;
            if (j + 1 < rounds) {
                tw = ew[wv][grp][j + 1];
                ra = *(const int4*)(hbf + (size_t)__float_as_int(tw.x) * NHID + fl * 8);
            }
            acc[0] = fmaf(w, (float)cur.h[0], acc[0]);
            acc[1] = fmaf(w, (float)cur.h[1], acc[1]);
            acc[2] = fmaf(w, (float)cur.h[2], acc[2]);
            acc[3] = fmaf(w, (float)cur.h[3], acc[3]);
            acc[4] = fmaf(w, (float)cur.h[4], acc[4]);
            acc[5] = fmaf(w, (float)cur.h[5], acc[5]);
            acc[6] = fmaf(w, (float)cur.h[6], acc[6]);
            acc[7] = fmaf(w, (float)cur.h[7], acc[7]);
        }
    }

    // div reduce within the 16-lane group
    #pragma unroll
    for (int m = 1; m <= 8; m <<= 1) divacc += __shfl_xor(divacc, m, 64);

    // self term + epilogue: each lane finishes its 8 features
    float w2v = isA ? w2Ah[n] : w2Ph[n];
    const half_t* xb = (isA ? xAh : xPh) + (size_t)n * NHID + fl * 8;
    union { int4 v; half_t h[8]; } xc;
    xc.v = *(const int4*)xb;
    #pragma unroll
    for (int j = 0; j < 8; ++j) acc[j] = fmaf(w2v, (float)xc.h[j], acc[j]);
    float dv = divacc + w2v;
    float inv = 1.f / dv;

    const float* a2 = isA ? a2nA : a2nP;
    float4 av0 = *(const float4*)(a2 + fl * 8);
    float4 av1 = *(const float4*)(a2 + fl * 8 + 4);
    float avf[8] = {av0.x, av0.y, av0.z, av0.w, av1.x, av1.y, av1.z, av1.w};

    float o[8], s = 0.f;
    #pragma unroll
    for (int j = 0; j < 8; ++j) {
        float v = acc[j] * inv;
        o[j] = v > 0.f ? v : (__expf(v) - 1.f);
        s = fmaf(o[j], avf[j], s);
    }
    #pragma unroll
    for (int m = 1; m <= 8; m <<= 1) s += __shfl_xor(s, m, 64);

    union { half_t h[8]; int4 v; } pk;
    #pragma unroll
    for (int j = 0; j < 8; ++j) pk.h[j] = (half_t)o[j];
    *(int4*)((isA ? hAout : hPout) + (size_t)n * NHID + fl * 8) = pk.v;
    if (fl == 0) (isA ? h1Aout : h1Pout)[n] = s;
}

extern "C" void kernel_launch(void* const* d_in, const int* in_sizes, int n_in,
                              void* d_out, int out_size, void* d_ws, size_t ws_size,
                              hipStream_t stream)
{
    const float* x_A  = (const float*)d_in[0];
    const float* x_P  = (const float*)d_in[1];
    const int*   sAP  = (const int*)d_in[2];
    const int*   tAP  = (const int*)d_in[3];
    const int*   sPA  = (const int*)d_in[4];
    const int*   tPA  = (const int*)d_in[5];
    const float* W1_A = (const float*)d_in[6];
    const float* b1_A = (const float*)d_in[7];
    const float* W1_P = (const float*)d_in[8];
    const float* b1_P = (const float*)d_in[9];
    const float* attn1 = (const float*)d_in[10];
    const float* attn2 = (const float*)d_in[11];
    const float* W2   = (const float*)d_in[12];
    const float* b2   = (const float*)d_in[13];
    float* out = (float*)d_out;
    int nE = in_sizes[2];

    char* ws = (char*)d_ws;
    size_t off = 0;
    auto alloc = [&](size_t bytes) -> void* {
        void* p = ws + off;
        off += (bytes + 255) & ~(size_t)255;
        return p;
    };
    half_t* xAh  = (half_t*)alloc((size_t)NA * NHID * 2);
    half_t* xPh  = (half_t*)alloc((size_t)NP * NHID * 2);
    half_t* hAh[2] = {(half_t*)alloc((size_t)NA * NHID * 2),
                      (half_t*)alloc((size_t)NA * NHID * 2)};
    half_t* hPh[2] = {(half_t*)alloc((size_t)NP * NHID * 2),
                      (half_t*)alloc((size_t)NP * NHID * 2)};
    float* x1A = (float*)alloc((size_t)3 * NA * 4);
    float* w2A = (float*)alloc((size_t)3 * NA * 4);
    float* x1P = (float*)alloc((size_t)3 * NP * 4);
    float* w2P = (float*)alloc((size_t)3 * NP * 4);
    float* h1Ai = (float*)alloc(NA * 4);
    float* h1Pi = (float*)alloc(NP * 4);
    float* h1Ab[2] = {(float*)alloc(NA * 4), (float*)alloc(NA * 4)};
    float* h1Pb[2] = {(float*)alloc(NP * 4), (float*)alloc(NP * 4)};
    int* cntA  = (int*)alloc(NA * 4);
    int* cntP  = (int*)alloc(NP * 4);
    int* slotsA = (int*)alloc((size_t)NA * CAP_A * 4);
    int* slotsP = (int*)alloc((size_t)NP * CAP_P * 4);
    half_t* WtA = (half_t*)alloc((size_t)NHID * NIN * 2);
    half_t* WtP = (half_t*)alloc((size_t)NHID * NIN * 2);
    half_t* Wt2 = (half_t*)alloc((size_t)NOUT * NHID * 2);

    // weights -> f16 transposed + cnt zeroing (before fused kernel)
    int prepN = 2 * NHID * NIN + NOUT * NHID + NA + NP;
    prep_all<<<(prepN + 255) / 256, 256, 0, stream>>>(W1_A, W1_P, W2, WtA, WtP, Wt2,
                                                      cntA, cntP);

    // FUSED: proj(A) + proj(P) + padded-CSR fill in one dispatch
    int gA = (NA + 63) / 64, gP = (NP + 63) / 64;
    int gAB = gA + gP;
    int fillBlocks = (2 * nE + 255) / 256;
    fused_proj_fill<<<gAB + fillBlocks, 256, 0, stream>>>(
        x_A, x_P, WtA, WtP, b1_A, b1_P, xAh, xPh,
        sAP, tAP, sPA, tPA, cntA, slotsA, cntP, slotsP,
        nE, gA, gAB);

    // x-side scalars for all hops (4 nodes/wave)
    xdots_kernel<<<(NA + NP + 15) / 16, 256, 0, stream>>>(
        xAh, xPh, attn1, attn2, x1A, w2A, h1Ai, x1P, w2P, h1Pi);

    const half_t* hAg = xAh;
    const half_t* hPg = xPh;
    const float* h1Ac = h1Ai;
    const float* h1Pc = h1Pi;

    for (int i = 0; i < HOPS; ++i) {
        int last = (i == HOPS - 1);
        int nodes = last ? NA : (NA + NP);
        const float* a2nA_ = last ? attn2 : attn2 + (size_t)((i + 1) * 2 + 1) * NHID;
        const float* a2nP_ = last ? attn2 : attn2 + (size_t)((i + 1) * 2 + 0) * NHID;
        agg_fused<<<(nodes + 15) / 16, 256, 0, stream>>>(
            xAh, xPh, hAg, hPg,
            x1A + (size_t)i * NA, x1P + (size_t)i * NP,
            w2A + (size_t)i * NA, w2P + (size_t)i * NP,
            h1Ac, h1Pc,
            cntA, slotsA, cntP, slotsP,
            a2nA_, a2nP_,
            hAh[i & 1], hPh[i & 1], h1Ab[i & 1], h1Pb[i & 1],
            nodes);
        hAg = hAh[i & 1]; hPg = hPh[i & 1];
        h1Ac = h1Ab[i & 1]; h1Pc = h1Pb[i & 1];
    }

    out_mfma<<<(NA + 63) / 64, 256, 0, stream>>>(hAg, Wt2, b2, out, NA);
}